// Round 5
// baseline (475.026 us; speedup 1.0000x reference)
//
#include <hip/hip_runtime.h>
#include <hip/hip_bf16.h>
#include <stdint.h>

#define NTOK 16384
#define DDIM 4096
#define NEXP 128
#define BM 32
#define BK 32
#define NT (DDIM / BK)   // 128 k-tiles
#define NBUF 4

typedef __attribute__((ext_vector_type(8))) short short8;   // 8 bf16 = 4 VGPRs (MFMA A/B frag)
typedef __attribute__((ext_vector_type(4))) float f32x4;    // MFMA C/D frag
typedef __attribute__((address_space(1))) const uint32_t gu32;
typedef __attribute__((address_space(3))) uint32_t lu32;

// async global->LDS, 16B per lane. Dest must be wave-uniform base + lane*16 (linear).
__device__ __forceinline__ void gload16(const void* g, void* l) {
    __builtin_amdgcn_global_load_lds((gu32*)g, (lu32*)l, 16, 0, 0);
}

// fp32 -> (hi, lo) bf16 pair, both RNE. f ~= hi + lo with |err| <~ 2^-17 |f|.
__device__ __forceinline__ void split_bf16(float f, uint32_t& h, uint32_t& l) {
    uint32_t u = __float_as_uint(f);
    h = (u + 0x7FFFu + ((u >> 16) & 1u)) >> 16;
    float r = f - __uint_as_float(h << 16);
    uint32_t v = __float_as_uint(r);
    l = (v + 0x7FFFu + ((v >> 16) & 1u)) >> 16;
}

// ---- kernel 1: split wg_weight [128][4096] fp32 -> w_hi, w_lo bf16 in ws ----
__global__ void prep_w(const float* __restrict__ w,
                       uint16_t* __restrict__ whi, uint16_t* __restrict__ wlo) {
    int i = (blockIdx.x * blockDim.x + threadIdx.x) * 4;
    float4 f = *(const float4*)(w + i);
    uint32_t h0, h1, h2, h3, l0, l1, l2, l3;
    split_bf16(f.x, h0, l0);
    split_bf16(f.y, h1, l1);
    split_bf16(f.z, h2, l2);
    split_bf16(f.w, h3, l3);
    uint2 hv = make_uint2(h0 | (h1 << 16), h2 | (h3 << 16));
    uint2 lv = make_uint2(l0 | (l1 << 16), l2 | (l3 << 16));
    *(uint2*)(whi + i) = hv;
    *(uint2*)(wlo + i) = lv;
}

// ---- kernel 2: logits = x @ w^T, counted-vmcnt 4-deep pipeline (T3+T4) ----
// BM=32 tokens x 128 experts, 256 threads = 4 waves (wave = 32-expert column).
// BK=32: tile = A raw f32 4KB + B hi/lo 8+8KB = 20KB; NBUF=4 ring = 80KB LDS
// -> 2 blocks/CU. ALL staging via global_load_lds (A raw f32, split at
// fragment-build). 5 gloads/tile, 3 tiles in flight; per-iter barrier is
//   s_waitcnt vmcnt(10) lgkmcnt(0); s_barrier
// -- loads for t+2,t+3 stay in flight ACROSS the barrier (never drain to 0).
// Tail iters stage a dummy (clamped) tile to keep the vmcnt FIFO count exact.
// Swizzles (re-derived for BK=32):
//   A [32 rows][8 chunks]: LDS(r,j) = global(r, j^(r&7)); frag reads 2 chunks
//     (2q)^(r&7), (2q+1)^(r&7): bank-quad = j' -> 8 distinct / 16 lanes = 2-way (free).
//   B [128 rows][4 chunks]: key bx(r) = (r&3)^((r>>2)&1); LDS(r,j) = global(r, j^bx(r));
//     frag reads chunk q^bx(r): bank-quad = (4r+slot)%8 -> 8 distinct = 2-way (free).
__global__ __launch_bounds__(256, 2) void gemm_logits(
    const float* __restrict__ x,
    const uint16_t* __restrict__ whi, const uint16_t* __restrict__ wlo,
    float* __restrict__ S)
{
    __shared__ float    sA[NBUF * BM * BK];      // raw f32  4 KB/buf
    __shared__ uint16_t sBh[NBUF * NEXP * BK];   // bf16 hi  8 KB/buf
    __shared__ uint16_t sBl[NBUF * NEXP * BK];   // bf16 lo  8 KB/buf

    const int tid  = threadIdx.x;
    const int lane = tid & 63;
    const int wave = tid >> 6;     // expert column: experts wave*32 .. +31
    const int q = lane >> 4;       // quad id, k-chunk selector
    const int c = lane & 15;       // row (A) / col (B) within 16
    const int m0 = blockIdx.x * BM;

    // A staging: thread t -> row ar=t>>3, LDS slot j=t&7; src chunk jj=j^(ar&7)
    const int ar = tid >> 3;
    const int ajj = (tid & 7) ^ (ar & 7);
    const float* xsrc = x + (size_t)(m0 + ar) * DDIM + ajj * 4;
    const int adst = tid * 4;                       // f32 elems (16B/thread)

    // B staging: chunks ch0=tid, ch1=tid+256; row=ch>>2, slot=ch&3,
    // src chunk jj = slot ^ bx(row). Row+64 has identical bx -> shared jj.
    const int br  = tid >> 2;
    const int bslot = tid & 3;
    const int bx  = (br & 3) ^ ((br >> 2) & 1);
    const size_t bsrc = (size_t)br * DDIM + (size_t)(bslot ^ bx) * 8;
    const int bdst0 = tid * 8, bdst1 = (tid + 256) * 8;   // bf16 elems

    f32x4 acc[2][2];
    #pragma unroll
    for (int mt = 0; mt < 2; ++mt)
        #pragma unroll
        for (int nt = 0; nt < 2; ++nt)
            acc[mt][nt] = (f32x4){0.f, 0.f, 0.f, 0.f};

    auto stage = [&](int bi, int kt) {
        const int kk = kt * BK;                               // elem offset
        gload16(xsrc + kk, &sA[bi * BM * BK + adst]);
        gload16(whi + bsrc + kk, &sBh[bi * NEXP * BK + bdst0]);
        gload16(whi + bsrc + (size_t)64 * DDIM + kk, &sBh[bi * NEXP * BK + bdst1]);
        gload16(wlo + bsrc + kk, &sBl[bi * NEXP * BK + bdst0]);
        gload16(wlo + bsrc + (size_t)64 * DDIM + kk, &sBl[bi * NEXP * BK + bdst1]);
    };

    auto compute = [&](int bi) {
        const float* A = &sA[bi * BM * BK];
        const uint16_t* Bh = &sBh[bi * NEXP * BK];
        const uint16_t* Bl = &sBl[bi * NEXP * BK];
        short8 ah[2], al[2], bh[2], bl[2];
        #pragma unroll
        for (int mt = 0; mt < 2; ++mt) {
            const int row = mt * 16 + c;
            const int rb = row * BK;
            const float4 x0 = *(const float4*)&A[rb + ((((q << 1)    ) ^ (row & 7)) << 2)];
            const float4 x1 = *(const float4*)&A[rb + ((((q << 1) | 1) ^ (row & 7)) << 2)];
            const float f[8] = {x0.x, x0.y, x0.z, x0.w, x1.x, x1.y, x1.z, x1.w};
            short8 hv, lv;
            #pragma unroll
            for (int j = 0; j < 8; ++j) {
                uint32_t hh, ll;
                split_bf16(f[j], hh, ll);
                hv[j] = (short)hh;
                lv[j] = (short)ll;
            }
            ah[mt] = hv;
            al[mt] = lv;
        }
        #pragma unroll
        for (int nt = 0; nt < 2; ++nt) {
            const int row = wave * 32 + nt * 16 + c;
            const int slot = q ^ ((row & 3) ^ ((row >> 2) & 1));
            const int off = row * BK + slot * 8;
            bh[nt] = *(const short8*)&Bh[off];
            bl[nt] = *(const short8*)&Bl[off];
        }
        #pragma unroll
        for (int mt = 0; mt < 2; ++mt)
            #pragma unroll
            for (int nt = 0; nt < 2; ++nt) {
                acc[mt][nt] = __builtin_amdgcn_mfma_f32_16x16x32_bf16(al[mt], bh[nt], acc[mt][nt], 0, 0, 0);
                acc[mt][nt] = __builtin_amdgcn_mfma_f32_16x16x32_bf16(ah[mt], bl[nt], acc[mt][nt], 0, 0, 0);
                acc[mt][nt] = __builtin_amdgcn_mfma_f32_16x16x32_bf16(ah[mt], bh[nt], acc[mt][nt], 0, 0, 0);
            }
    };

    // ---- prologue: fill 3 pipeline stages, wait for tile 0 only ----
    stage(0, 0);
    stage(1, 1);
    stage(2, 2);
    asm volatile("s_waitcnt vmcnt(10) lgkmcnt(0)\n\ts_barrier" ::: "memory");

    // ---- main loop: stage t+3, compute t, counted-vmcnt barrier ----
    #pragma unroll 4
    for (int t = 0; t < NT; ++t) {
        const int ts = (t + 3 < NT) ? t + 3 : NT - 1;   // dummy stage at tail keeps count exact
        stage((t + 3) & 3, ts);
        compute(t & 3);
        // tile t+1 guaranteed landed (own-wave count <=10 = tiles t+2,t+3);
        // lgkmcnt(0) drains our ds_reads of tile t before its buffer is reused.
        asm volatile("s_waitcnt vmcnt(10) lgkmcnt(0)\n\ts_barrier" ::: "memory");
    }

    // ---- epilogue: C/D layout col=lane&15, row=(lane>>4)*4+reg (m89-verified) ----
    #pragma unroll
    for (int mt = 0; mt < 2; ++mt)
        #pragma unroll
        for (int nt = 0; nt < 2; ++nt) {
            const int e = wave * 32 + nt * 16 + c;
            #pragma unroll
            for (int r = 0; r < 4; ++r) {
                const int tok = m0 + mt * 16 + q * 4 + r;
                S[(size_t)tok * NEXP + e] = acc[mt][nt][r];
            }
        }
}

// ---- kernel 3: masked softmax + adaptive top-k, FOUR tokens per wave ----
// (unchanged from R4 -- held fixed so the gemm delta is attributable)
__global__ __launch_bounds__(256) void postproc(
    float* __restrict__ S, const float* __restrict__ mask,
    float* __restrict__ topk_out)
{
    const int lane = threadIdx.x & 63;
    const int wave = threadIdx.x >> 6;
    const int g  = lane >> 4;           // group (token) within wave
    const int gl = lane & 15;           // lane within group
    const int tok = blockIdx.x * 16 + wave * 4 + g;
    float* row = S + (size_t)tok * NEXP;

    float v[8];
    bool act[8];
    int cnt = 0;
    #pragma unroll
    for (int j = 0; j < 8; ++j) {
        v[j] = row[gl + 16 * j];
        act[j] = (mask[gl + 16 * j] != 0.f);
        cnt += act[j] ? 1 : 0;
    }
    int active = cnt;
    #pragma unroll
    for (int off = 8; off; off >>= 1) active += __shfl_xor(active, off);

    // masked max (group reduce, 4 steps)
    float mx = -3.0e38f;
    #pragma unroll
    for (int j = 0; j < 8; ++j) mx = fmaxf(mx, act[j] ? v[j] : -3.0e38f);
    #pragma unroll
    for (int off = 8; off; off >>= 1) mx = fmaxf(mx, __shfl_xor(mx, off));

    float sum = 0.f;
    #pragma unroll
    for (int j = 0; j < 8; ++j) {
        v[j] = act[j] ? __expf(v[j] - mx) : 0.f;
        sum += v[j];
    }
    #pragma unroll
    for (int off = 8; off; off >>= 1) sum += __shfl_xor(sum, off);

    const float inv = 1.0f / sum;
    #pragma unroll
    for (int j = 0; j < 8; ++j) {
        v[j] = v[j] * inv + 1e-14f;
        row[gl + 16 * j] = v[j];
    }

    // adaptive top-k: extract maxima until cumulative mass >= 0.5.
    // Sequential adds in descending order == reference's sorted cumsum order.
    // Hard bound k < NEXP guarantees termination.
    float cum = 0.f;
    int k = 0;
    bool done = false;
    while (__ballot(!done)) {
        if (!done) {
            float mv = v[0];
            #pragma unroll
            for (int j = 1; j < 8; ++j) mv = fmaxf(mv, v[j]);
            #pragma unroll
            for (int off = 8; off; off >>= 1) mv = fmaxf(mv, __shfl_xor(mv, off));
            cum += mv;
            ++k;
            // remove exactly one instance of the max (ties one at a time)
            bool has = false;
            #pragma unroll
            for (int j = 0; j < 8; ++j) has |= (v[j] == mv);
            unsigned int m16 = (unsigned int)((__ballot(has) >> (g * 16)) & 0xFFFFull);
            int first = __ffs(m16) - 1;
            if (gl == first) {
                bool cleared = false;
                #pragma unroll
                for (int j = 0; j < 8; ++j) {
                    if (!cleared && v[j] == mv) { v[j] = -1.f; cleared = true; }
                }
            }
            done = (cum >= 0.5f) || (k >= NEXP);
        }
    }
    int topk = k < active ? k : active;
    if (gl == 0) topk_out[tok] = (float)topk;
}

extern "C" void kernel_launch(void* const* d_in, const int* in_sizes, int n_in,
                              void* d_out, int out_size, void* d_ws, size_t ws_size,
                              hipStream_t stream) {
    (void)in_sizes; (void)n_in; (void)out_size; (void)ws_size;
    const float* x    = (const float*)d_in[0];
    const float* w    = (const float*)d_in[1];
    const float* mask = (const float*)d_in[2];

    float* S    = (float*)d_out;                  // [16384,128] scores (also logit scratch)
    float* topk = S + (size_t)NTOK * NEXP;        // [16384] top_k as float

    uint16_t* whi = (uint16_t*)d_ws;              // [128,4096] bf16 hi
    uint16_t* wlo = whi + (size_t)NEXP * DDIM;    // [128,4096] bf16 lo

    hipLaunchKernelGGL(prep_w, dim3((NEXP * DDIM) / (256 * 4)), dim3(256), 0, stream,
                       w, whi, wlo);
    hipLaunchKernelGGL(gemm_logits, dim3(NTOK / BM), dim3(256), 0, stream,
                       x, whi, wlo, S);
    hipLaunchKernelGGL(postproc, dim3(NTOK / 16), dim3(256), 0, stream,
                       S, mask, topk);
}